// Round 18
// baseline (75.403 us; speedup 1.0000x reference)
//
#include <hip/hip_runtime.h>

#define IN_FEATS 256
#define HID 32
#define NUM_EMBED 54012
#define N_NODES 65536
#define N_EDGES 1048576
#define BATCH 4096

#define NR 256               // node ranges (dst >> 8), 256 nodes each
#define NB 512               // binsort blocks
#define EPB (N_EDGES / NB)   // 2048 edges per block
#define PBCAP 32             // per-(block,range) sub-segment slots (mean 8)
#define HCAP 24              // bin slots per (node, half); Poisson(8), P(>24)~3e-7
#define OVF_CAP 65536
#define GEMMB 1024           // 4096 node row-tiles / 4 waves per block
#define NTILEN 4096          // 65536 / 16
#define W1P 272              // padded k-stride (u16) for W1t LDS

typedef unsigned short u16t;
typedef unsigned int u32t;
typedef __attribute__((ext_vector_type(8))) short bf16x8;
typedef __attribute__((ext_vector_type(4))) float f32x4;

__device__ __forceinline__ float bf2f(u16t u) {
    return __uint_as_float(((u32t)u) << 16);
}
__device__ __forceinline__ u16t f2bf(float f) {
    u32t x = __float_as_uint(f);
    return (u16t)((x + 0x7FFFu + ((x >> 16) & 1u)) >> 16);   // RNE
}
__device__ __forceinline__ u32t cvt_pk(float lo, float hi) {
    u32t r;
    asm("v_cvt_pk_bf16_f32 %0, %1, %2" : "=v"(r) : "v"(lo), "v"(hi));
    return r;
}

// sum of up to m (<=24) bf16 feature rows listed in one half-cell (3 int4)
__device__ __forceinline__ float half_sum_bf(const int4* cell, int m,
                                             const u16t* __restrict__ feat1, int c) {
    int4 c0 = cell[0];
    u32t w[4] = {(u32t)c0.x, (u32t)c0.y, (u32t)c0.z, (u32t)c0.w};
    float va[8];
#pragma unroll
    for (int k = 0; k < 4; ++k) {
        va[2 * k + 0] = bf2f(feat1[((size_t)(w[k] & 0xFFFFu) << 5) + c]);
        va[2 * k + 1] = bf2f(feat1[((size_t)(w[k] >> 16) << 5) + c]);
    }
    float acc = 0.f;
#pragma unroll
    for (int j = 0; j < 8; ++j) acc += (m > j) ? va[j] : 0.f;
    if (m > 8) {
        int4 c1 = cell[1];
        u32t x[4] = {(u32t)c1.x, (u32t)c1.y, (u32t)c1.z, (u32t)c1.w};
        float vb[8];
#pragma unroll
        for (int k = 0; k < 4; ++k) {
            vb[2 * k + 0] = bf2f(feat1[((size_t)(x[k] & 0xFFFFu) << 5) + c]);
            vb[2 * k + 1] = bf2f(feat1[((size_t)(x[k] >> 16) << 5) + c]);
        }
#pragma unroll
        for (int j = 0; j < 8; ++j) acc += (m > 8 + j) ? vb[j] : 0.f;
        if (m > 16) {
            int4 c2 = cell[2];
            u32t y[4] = {(u32t)c2.x, (u32t)c2.y, (u32t)c2.z, (u32t)c2.w};
            float vc[8];
#pragma unroll
            for (int k = 0; k < 4; ++k) {
                vc[2 * k + 0] = bf2f(feat1[((size_t)(y[k] & 0xFFFFu) << 5) + c]);
                vc[2 * k + 1] = bf2f(feat1[((size_t)(y[k] >> 16) << 5) + c]);
            }
#pragma unroll
            for (int j = 0; j < 8; ++j) acc += (m > 16 + j) ? vc[j] : 0.f;
        }
    }
    return acc;
}

// same but f32 rows (agg1)
__device__ __forceinline__ float half_sum_f32(const int4* cell, int m,
                                              const float* __restrict__ agg1, int c) {
    int4 c0 = cell[0];
    u32t w[4] = {(u32t)c0.x, (u32t)c0.y, (u32t)c0.z, (u32t)c0.w};
    float va[8];
#pragma unroll
    for (int k = 0; k < 4; ++k) {
        va[2 * k + 0] = agg1[((size_t)(w[k] & 0xFFFFu) << 5) + c];
        va[2 * k + 1] = agg1[((size_t)(w[k] >> 16) << 5) + c];
    }
    float acc = 0.f;
#pragma unroll
    for (int j = 0; j < 8; ++j) acc += (m > j) ? va[j] : 0.f;
    if (m > 8) {
        int4 c1 = cell[1];
        u32t x[4] = {(u32t)c1.x, (u32t)c1.y, (u32t)c1.z, (u32t)c1.w};
        float vb[8];
#pragma unroll
        for (int k = 0; k < 4; ++k) {
            vb[2 * k + 0] = agg1[((size_t)(x[k] & 0xFFFFu) << 5) + c];
            vb[2 * k + 1] = agg1[((size_t)(x[k] >> 16) << 5) + c];
        }
#pragma unroll
        for (int j = 0; j < 8; ++j) acc += (m > 8 + j) ? vb[j] : 0.f;
        if (m > 16) {
            int4 c2 = cell[2];
            u32t y[4] = {(u32t)c2.x, (u32t)c2.y, (u32t)c2.z, (u32t)c2.w};
            float vc[8];
#pragma unroll
            for (int k = 0; k < 4; ++k) {
                vc[2 * k + 0] = agg1[((size_t)(y[k] & 0xFFFFu) << 5) + c];
                vc[2 * k + 1] = agg1[((size_t)(y[k] >> 16) << 5) + c];
            }
#pragma unroll
            for (int j = 0; j < 8; ++j) acc += (m > 16 + j) ? vc[j] : 0.f;
        }
    }
    return acc;
}

// ---------------------------------------------------------------------------
// Phase A (fused, blockIdx-dispatched):
//   [0, NB)            : binsort — LDS hist + fixed sub-segments, 0 glb atomics
//   [NB, NB+GEMMB)     : feat1[n] = bf16(embed[idx[n]] @ W1) via MFMA 16x16x32
//                        (gather fused into GEMM; no tmpb)
//   [NB+GEMMB, +65)    : fold W2/Wfc/b2/bfc -> M1, M2, bias (+ ovf_cnt init)
// ---------------------------------------------------------------------------
__global__ void k_phaseA(const float* __restrict__ embed, const float* __restrict__ W1,
                         const int* __restrict__ idx, u16t* __restrict__ feat1,
                         const int* __restrict__ src, const int* __restrict__ dst,
                         u32t* __restrict__ subseg, u16t* __restrict__ hcnt,
                         int* __restrict__ ovf_cnt, int* __restrict__ ovf,
                         const float* __restrict__ W2, const float* __restrict__ b2,
                         const float* __restrict__ Wfc, const float* __restrict__ bfc,
                         float* __restrict__ M1, float* __restrict__ M2,
                         float* __restrict__ bias) {
    __shared__ __align__(16) char smem[32 * W1P * 2];   // 17408 B
    int b = blockIdx.x;
    int t = threadIdx.x;

    if (b < NB) {
        // ---------------- binsort (zero global atomics) ----------------
        int bb = b;
        u32t* hist = (u32t*)smem;            // [256]
        u32t* cur  = hist + 256;             // [256]
        u32t* epak = cur + 256;              // [EPB]
        unsigned char* erng = (unsigned char*)(epak + EPB);   // [EPB]
        hist[t] = 0;
        cur[t] = 0;
        __syncthreads();
        int base = bb * EPB;
#pragma unroll
        for (int k = 0; k < EPB / 256; ++k) {
            int i = k * 256 + t;
            int s = __builtin_nontemporal_load(&src[base + i]);
            int d = __builtin_nontemporal_load(&dst[base + i]);
            int r = d >> 8;
            epak[i] = (u32t)s | ((u32t)(d & 255) << 16);
            erng[i] = (unsigned char)r;
            atomicAdd(&hist[r], 1u);
        }
        __syncthreads();
        hcnt[t * NB + bb] = (u16t)min(hist[t], (u32t)PBCAP);
#pragma unroll
        for (int k = 0; k < EPB / 256; ++k) {
            int i = k * 256 + t;
            u32t w = epak[i];
            int r = erng[i];
            u32t p = atomicAdd(&cur[r], 1u);
            if (p < PBCAP) {
                subseg[((size_t)((u32t)r * NB + bb)) * PBCAP + p] = w;
            } else {
                int o = atomicAdd(ovf_cnt, 1);
                u32t dfull = ((u32t)r << 8) | (w >> 16);
                if (o < OVF_CAP) ovf[o] = (int)((w & 0xFFFFu) | (dfull << 16));
            }
        }
    } else if (b < NB + GEMMB) {
        // ------- MFMA GEMM, gather-fused: feat1[n] = bf16(embed[idx[n]] @ W1) -------
        u16t* w1t = (u16t*)smem;   // [32 cols][W1P k]
        for (int i4 = t; i4 < IN_FEATS * HID / 4; i4 += 256) {
            float4 v = ((const float4*)W1)[i4];
            int i = i4 * 4;
            int k = i >> 5, c = i & 31;        // 4 consecutive c, same k
            w1t[(c + 0) * W1P + k] = f2bf(v.x);
            w1t[(c + 1) * W1P + k] = f2bf(v.y);
            w1t[(c + 2) * W1P + k] = f2bf(v.z);
            w1t[(c + 3) * W1P + k] = f2bf(v.w);
        }
        __syncthreads();

        int lane = t & 63;
        int wv = t >> 6;
        int tile = (b - NB) * 4 + wv;          // < NTILEN always
        int n0 = tile * 16;

        int node = n0 + (lane & 15);
        int arow = idx[node];
        int kq = (lane >> 4) * 8;
        const float* Erow = embed + (size_t)arow * IN_FEATS + kq;

        int c = lane & 15;
        bf16x8 bf0[8], bf1[8];
        {
            const u16t* bp0 = w1t + (size_t)c * W1P + kq;
            const u16t* bp1 = w1t + (size_t)(c + 16) * W1P + kq;
#pragma unroll
            for (int kk = 0; kk < 8; ++kk) {
                bf0[kk] = *(const bf16x8*)(bp0 + kk * 32);
                bf1[kk] = *(const bf16x8*)(bp1 + kk * 32);
            }
        }

        f32x4 acc0 = {0.f, 0.f, 0.f, 0.f};
        f32x4 acc1 = {0.f, 0.f, 0.f, 0.f};
#pragma unroll
        for (int kk = 0; kk < 8; ++kk) {
            float4 p = *(const float4*)(Erow + kk * 32);
            float4 q = *(const float4*)(Erow + kk * 32 + 4);
            union { bf16x8 v; u32t u[4]; } a;
            a.u[0] = cvt_pk(p.x, p.y);
            a.u[1] = cvt_pk(p.z, p.w);
            a.u[2] = cvt_pk(q.x, q.y);
            a.u[3] = cvt_pk(q.z, q.w);
            acc0 = __builtin_amdgcn_mfma_f32_16x16x32_bf16(a.v, bf0[kk], acc0, 0, 0, 0);
            acc1 = __builtin_amdgcn_mfma_f32_16x16x32_bf16(a.v, bf1[kk], acc1, 0, 0, 0);
        }

        // D: row = n0 + (lane>>4)*4 + j, col = (lane&15) (+16 for acc1)
        int rbase = n0 + (lane >> 4) * 4;
#pragma unroll
        for (int j = 0; j < 4; ++j) {
            int rr = rbase + j;
            feat1[(size_t)rr * HID + c]      = f2bf(acc0[j]);
            feat1[(size_t)rr * HID + 16 + c] = f2bf(acc1[j]);
        }
    } else {
        // ---------------- fold (4 independent accumulators) ----------------
        int r = b - NB - GEMMB;   // 0..64
        int c = t;
        if (r < 32) {
            float p0 = 0.f, p1 = 0.f, p2 = 0.f, p3 = 0.f;
#pragma unroll
            for (int j = 0; j < 256; j += 4) {
                p0 += W2[r * 256 + j + 0] * Wfc[(j + 0) * 256 + c];
                p1 += W2[r * 256 + j + 1] * Wfc[(j + 1) * 256 + c];
                p2 += W2[r * 256 + j + 2] * Wfc[(j + 2) * 256 + c];
                p3 += W2[r * 256 + j + 3] * Wfc[(j + 3) * 256 + c];
            }
            M1[r * 256 + c] = (p0 + p1) + (p2 + p3);
        } else if (r < 64) {
            int k = r - 32;
            float p0 = 0.f, p1 = 0.f, p2 = 0.f, p3 = 0.f;
#pragma unroll
            for (int j = 0; j < 256; j += 4) {
                p0 += W2[k * 256 + j + 0] * Wfc[(256 + j + 0) * 256 + c];
                p1 += W2[k * 256 + j + 1] * Wfc[(256 + j + 1) * 256 + c];
                p2 += W2[k * 256 + j + 2] * Wfc[(256 + j + 2) * 256 + c];
                p3 += W2[k * 256 + j + 3] * Wfc[(256 + j + 3) * 256 + c];
            }
            M2[k * 256 + c] = (p0 + p1) + (p2 + p3);
        } else {
            if (t == 0) *ovf_cnt = 0;   // fused init (binsort overflow P ~1e-6)
            float p0 = 0.f, p1 = 0.f;
#pragma unroll
            for (int j = 0; j < 256; j += 2) {
                p0 += b2[j + 0] * (Wfc[(j + 0) * 256 + c] + Wfc[(256 + j + 0) * 256 + c]);
                p1 += b2[j + 1] * (Wfc[(j + 1) * 256 + c] + Wfc[(256 + j + 1) * 256 + c]);
            }
            bias[c] = bfc[c] + p0 + p1;
        }
    }
}

// ---------------------------------------------------------------------------
// K_pack: block (r,h) walks subseg[r][h*256..][:] (8-deep batched loads) into
// LDS cells [256 nodes][24 u16], flush to bins2 + cntAB half.
// ---------------------------------------------------------------------------
__global__ void k_pack(const u32t* __restrict__ subseg, const u16t* __restrict__ hcnt,
                       u32t* __restrict__ cntAB, u16t* __restrict__ bins2,
                       int* __restrict__ ovf_cnt, int* __restrict__ ovf) {
    __shared__ u16t cells[NR * HCAP];   // 12 KB
    __shared__ u32t cl[NR];             // 1 KB
    __shared__ u16t hc[NB / 2];         // 512 B
    int b = blockIdx.x;
    int t = threadIdx.x;
    int r = b >> 1, h = b & 1;
    for (int i = t; i < NR * HCAP / 2; i += 256) ((u32t*)cells)[i] = 0;
    cl[t] = 0;
    if (t < 128)
        ((u32t*)hc)[t] = ((const u32t*)(hcnt + (size_t)r * NB + h * 256))[t];
    __syncthreads();

    const u32t* segr = subseg + ((size_t)r * NB + h * 256) * PBCAP;   // 32 KB
    for (int base_lin = 0; base_lin < 256 * PBCAP; base_lin += 2048) {
        u32t wbuf[8];
        int vld[8];
#pragma unroll
        for (int u = 0; u < 8; ++u) {
            int lin = base_lin + u * 256 + t;
            int bb = lin >> 5;             // PBCAP = 32
            int slot = lin & (PBCAP - 1);
            vld[u] = (slot < (int)hc[bb]);
            wbuf[u] = __builtin_nontemporal_load(&segr[lin]);
        }
#pragma unroll
        for (int u = 0; u < 8; ++u) {
            if (vld[u]) {
                u32t w = wbuf[u];
                int dl = (int)(w >> 16) & 255;
                u32t p = atomicAdd(&cl[dl], 1u);
                if (p < HCAP) {
                    cells[dl * HCAP + p] = (u16t)(w & 0xFFFFu);
                } else {
                    int o = atomicAdd(ovf_cnt, 1);
                    u32t dfull = ((u32t)r << 8) | (u32t)dl;
                    if (o < OVF_CAP) ovf[o] = (int)((w & 0xFFFFu) | (dfull << 16));
                }
            }
        }
    }
    __syncthreads();
    u32t* dst32 = (u32t*)(bins2) + ((size_t)h * N_NODES + ((size_t)r << 8)) * (HCAP / 2);
    for (int i = t; i < NR * HCAP / 2; i += 256)
        dst32[i] = ((const u32t*)cells)[i];
    ((u16t*)cntAB)[(((size_t)r << 8) + t) * 2 + h] = (u16t)min(cl[t], 65535u);
}

// ---------------------------------------------------------------------------
// SpMM1: agg1[v][c] = relu(sum of both halves + ovf-scan + b1[c])
// ---------------------------------------------------------------------------
__global__ void k_spmm1(const u16t* __restrict__ feat1,
                        const u32t* __restrict__ cntAB, const u16t* __restrict__ bins2,
                        const int* __restrict__ ovf_cnt, const int* __restrict__ ovf,
                        const float* __restrict__ b1, float* __restrict__ agg1) {
    int t = blockIdx.x * 256 + threadIdx.x;
    int v = t >> 5, c = t & 31;
    u32t cw = cntAB[v];
    int mA = min((int)(cw & 0xFFFFu), HCAP);
    int mB = min((int)(cw >> 16), HCAP);
    const int4* cellA = (const int4*)(bins2 + (size_t)v * HCAP);
    const int4* cellB = (const int4*)(bins2 + ((size_t)N_NODES + v) * HCAP);
    float acc = half_sum_bf(cellA, mA, feat1, c) + half_sum_bf(cellB, mB, feat1, c);

    int total = min(*ovf_cnt, OVF_CAP);
    for (int i = 0; i < total; ++i) {
        u32t e = (u32t)ovf[i];
        if ((e >> 16) == (u32t)v)
            acc += bf2f(feat1[((size_t)(e & 0xFFFFu) << 5) + c]);
    }
    agg1[t] = fmaxf(acc + b1[c], 0.f);
}

// ---------------------------------------------------------------------------
// K_tail: fused spmm2 (8 pairs per block) + final GEMM.
// ---------------------------------------------------------------------------
__global__ void k_tail(const float* __restrict__ agg1,
                       const u32t* __restrict__ cntAB, const u16t* __restrict__ bins2,
                       const int* __restrict__ ovf_cnt, const int* __restrict__ ovf,
                       const int* __restrict__ g1, const int* __restrict__ g2,
                       const float* __restrict__ M1, const float* __restrict__ M2,
                       const float* __restrict__ bias,
                       float* __restrict__ out) {
    __shared__ float a1s[8][HID];
    __shared__ float a2s[8][HID];
    int i0 = blockIdx.x * 8;
    int tid = threadIdx.x;
    int sg = tid >> 5, c = tid & 31;

    for (int side = 0; side < 2; ++side) {
        int slot = i0 + sg;
        int v = side ? g2[slot] : g1[slot];
        u32t cw = cntAB[v];
        int mA = min((int)(cw & 0xFFFFu), HCAP);
        int mB = min((int)(cw >> 16), HCAP);
        const int4* cellA = (const int4*)(bins2 + (size_t)v * HCAP);
        const int4* cellB = (const int4*)(bins2 + ((size_t)N_NODES + v) * HCAP);
        float acc = half_sum_f32(cellA, mA, agg1, c) + half_sum_f32(cellB, mB, agg1, c);

        int total = min(*ovf_cnt, OVF_CAP);
        for (int i = 0; i < total; ++i) {
            u32t e = (u32t)ovf[i];
            if ((e >> 16) == (u32t)v)
                acc += agg1[((size_t)(e & 0xFFFFu) << 5) + c];
        }
        if (side) a2s[sg][c] = acc;
        else      a1s[sg][c] = acc;
    }
    __syncthreads();

    int cc = tid;
    float acc[8];
#pragma unroll
    for (int q = 0; q < 8; ++q) acc[q] = bias[cc];
#pragma unroll
    for (int k = 0; k < HID; ++k) {
        float m1 = M1[k * 256 + cc];
        float m2 = M2[k * 256 + cc];
#pragma unroll
        for (int q = 0; q < 8; ++q)
            acc[q] += a1s[q][k] * m1 + a2s[q][k] * m2;
    }
#pragma unroll
    for (int q = 0; q < 8; ++q)
        out[(size_t)(i0 + q) * 256 + cc] = fmaxf(acc[q], 0.f);
}

// ---------------------------------------------------------------------------
extern "C" void kernel_launch(void* const* d_in, const int* in_sizes, int n_in,
                              void* d_out, int out_size, void* d_ws, size_t ws_size,
                              hipStream_t stream) {
    const int*   idx   = (const int*)d_in[0];
    const int*   src   = (const int*)d_in[1];
    const int*   dst   = (const int*)d_in[2];
    const int*   g1    = (const int*)d_in[3];
    const int*   g2    = (const int*)d_in[4];
    const float* embed = (const float*)d_in[5];
    const float* W1    = (const float*)d_in[6];
    const float* b1    = (const float*)d_in[7];
    const float* W2    = (const float*)d_in[8];
    const float* b2    = (const float*)d_in[9];
    const float* Wfc   = (const float*)d_in[10];
    const float* bfc   = (const float*)d_in[11];
    float* out = (float*)d_out;

    char* ws = (char*)d_ws;
    u16t*  feat1    = (u16t*)ws;   ws += (size_t)N_NODES * HID * 2;          // 4 MB
    float* agg1     = (float*)ws;  ws += (size_t)N_NODES * HID * 4;          // 8 MB
    float* M1       = (float*)ws;  ws += 32 * 256 * 4;
    float* M2       = (float*)ws;  ws += 32 * 256 * 4;
    float* bias     = (float*)ws;  ws += 256 * 4;
    u32t*  subseg   = (u32t*)ws;   ws += (size_t)NR * NB * PBCAP * 4;        // 16.8 MB
    u16t*  hcnt     = (u16t*)ws;   ws += (size_t)NR * NB * 2;                // 256 KB
    u32t*  cntAB    = (u32t*)ws;   ws += (size_t)N_NODES * 4;                // 256 KB
    u16t*  bins2    = (u16t*)ws;   ws += (size_t)2 * N_NODES * HCAP * 2;     // 6 MB
    int*   ovf_cnt  = (int*)ws;    ws += 64;
    int*   ovf      = (int*)ws;    ws += (size_t)OVF_CAP * 4;                // 256 KB

    k_phaseA<<<NB + GEMMB + 65, 256, 0, stream>>>(embed, W1, idx, feat1,
                                                  src, dst, subseg, hcnt, ovf_cnt, ovf,
                                                  W2, b2, Wfc, bfc, M1, M2, bias);

    k_pack<<<2 * NR, 256, 0, stream>>>(subseg, hcnt, cntAB, bins2, ovf_cnt, ovf);

    k_spmm1<<<(N_NODES * 32) / 256, 256, 0, stream>>>(feat1, cntAB, bins2,
                                                      ovf_cnt, ovf, b1, agg1);

    k_tail<<<BATCH / 8, 256, 0, stream>>>(agg1, cntAB, bins2, ovf_cnt, ovf,
                                          g1, g2, M1, M2, bias, out);
}